// Round 1
// baseline (417.078 us; speedup 1.0000x reference)
//
#include <hip/hip_runtime.h>

#define E_TOT   300000
#define DN      128
#define DOUT    128

typedef float  f32x4  __attribute__((ext_vector_type(4)));
typedef __bf16 bf16x8 __attribute__((ext_vector_type(8)));

__device__ __forceinline__ unsigned short f2bf(float f) {
    union { float f; unsigned int u; } v; v.f = f;
    return (unsigned short)((v.u + 0x7FFFu + ((v.u >> 16) & 1u)) >> 16);
}

// Repack W1 [384][256] -> bf16 [6][256][64]  (chunk, n, k)  and
//        W2 [256][128] -> bf16 [4][128][64]
__global__ void prep_weights(const float* __restrict__ W1,
                             const float* __restrict__ W2,
                             unsigned short* __restrict__ W1p,
                             unsigned short* __restrict__ W2p) {
    int t = blockIdx.x * 256 + threadIdx.x;
    if (t < 384 * 256) {
        int k = t >> 8, n = t & 255;
        W1p[(((k >> 6) << 8) + n) * 64 + (k & 63)] = f2bf(W1[t]);
    } else {
        int t2 = t - 384 * 256;
        int k = t2 >> 7, n = t2 & 127;
        W2p[(((k >> 6) << 7) + n) * 64 + (k & 63)] = f2bf(W2[t2]);
    }
}

__global__ __launch_bounds__(256, 3) void edge_mlp(
    const float* __restrict__ node_attr,
    const float* __restrict__ edge_attr,
    const int*   __restrict__ eidx,
    const unsigned short* __restrict__ W1p,
    const unsigned short* __restrict__ W2p,
    const float* __restrict__ b1,
    const float* __restrict__ b2,
    const float* __restrict__ ln_g,
    const float* __restrict__ ln_b,
    float* __restrict__ out)
{
    // 52224 B unioned: layer1 {Xc[64][72] @0, W1c[256][72] @4608}
    //                  layer2 {h[64][264] @0, W2c[128][72] @16896}
    __shared__ __align__(16) unsigned short smem[26112];
    __shared__ int sIdx[64], rIdx[64];

    unsigned short* Xc   = smem;           // [64][72]
    unsigned short* W1c  = smem + 4608;    // [256][72]
    unsigned short* hbuf = smem;           // [64][264]
    unsigned short* W2c  = smem + 16896;   // [128][72]

    const int tid  = threadIdx.x;
    const int wid  = tid >> 6;
    const int lane = tid & 63;
    const int quad = lane >> 4;
    const int l16  = lane & 15;
    const int eb   = blockIdx.x * 64;

    if (tid < 128) {
        int r = tid & 63;
        int e = eb + r; if (e >= E_TOT) e = E_TOT - 1;
        if (tid < 64) sIdx[r] = eidx[e];
        else          rIdx[r] = eidx[E_TOT + e];
    }

    f32x4 acc[4][4];
    #pragma unroll
    for (int i = 0; i < 4; ++i)
        #pragma unroll
        for (int j = 0; j < 4; ++j)
            acc[i][j] = (f32x4){0.f, 0.f, 0.f, 0.f};

    __syncthreads();

    // ---------- Layer 1: X[64x384] @ W1[384x256] ----------
    #pragma unroll 1
    for (int c = 0; c < 6; ++c) {
        if (c) __syncthreads();           // previous chunk's LDS reads done
        const int coloff = (c & 1) << 6;
        // gather + fp32->bf16 X chunk: 64 rows x 64 cols, 1024 float4 units
        #pragma unroll
        for (int i = 0; i < 4; ++i) {
            int id  = (i << 8) + tid;
            int row = id >> 4;
            int q4  = id & 15;
            const float* src;
            if (c < 2)      src = node_attr + (size_t)sIdx[row] * DN;
            else if (c < 4) src = node_attr + (size_t)rIdx[row] * DN;
            else {
                int e = eb + row; if (e >= E_TOT) e = E_TOT - 1;
                src = edge_attr + (size_t)e * DN;
            }
            float4 v = *(const float4*)(src + coloff + (q4 << 2));
            ushort4 p;
            p.x = f2bf(v.x); p.y = f2bf(v.y); p.z = f2bf(v.z); p.w = f2bf(v.w);
            *(ushort4*)(Xc + row * 72 + (q4 << 2)) = p;
        }
        // stage W1 chunk: contiguous [256][64] bf16 -> padded [256][72]
        const unsigned short* wsrc = W1p + c * (256 * 64);
        #pragma unroll
        for (int i = 0; i < 8; ++i) {
            int id = (i << 8) + tid;      // 0..2047 16B units
            *(uint4*)(W1c + (id >> 3) * 72 + ((id & 7) << 3)) =
                *(const uint4*)(wsrc + (id << 3));
        }
        __syncthreads();
        #pragma unroll
        for (int ks = 0; ks < 2; ++ks) {
            bf16x8 a[4];
            #pragma unroll
            for (int mt = 0; mt < 4; ++mt)
                a[mt] = *(const bf16x8*)(Xc + ((mt << 4) + l16) * 72 + (ks << 5) + (quad << 3));
            #pragma unroll
            for (int nt = 0; nt < 4; ++nt) {
                bf16x8 b = *(const bf16x8*)(W1c + ((wid << 6) + (nt << 4) + l16) * 72 + (ks << 5) + (quad << 3));
                #pragma unroll
                for (int mt = 0; mt < 4; ++mt)
                    acc[mt][nt] = __builtin_amdgcn_mfma_f32_16x16x32_bf16(a[mt], b, acc[mt][nt], 0, 0, 0);
            }
        }
    }

    // bias + ReLU -> hbuf (overlaps Xc/W1c; barrier guards the overwrite)
    float b1v[4];
    #pragma unroll
    for (int nt = 0; nt < 4; ++nt) b1v[nt] = b1[(wid << 6) + (nt << 4) + l16];
    __syncthreads();
    #pragma unroll
    for (int mt = 0; mt < 4; ++mt)
        #pragma unroll
        for (int nt = 0; nt < 4; ++nt)
            #pragma unroll
            for (int r = 0; r < 4; ++r) {
                int row = (mt << 4) + (quad << 2) + r;
                int col = (wid << 6) + (nt << 4) + l16;
                float v = acc[mt][nt][r] + b1v[nt];
                hbuf[row * 264 + col] = f2bf(v > 0.f ? v : 0.f);
            }
    __syncthreads();

    // ---------- Layer 2: h[64x256] @ W2[256x128] ----------
    f32x4 acc2[8];
    #pragma unroll
    for (int nt = 0; nt < 8; ++nt) acc2[nt] = (f32x4){0.f, 0.f, 0.f, 0.f};

    #pragma unroll 1
    for (int c2 = 0; c2 < 4; ++c2) {
        if (c2) __syncthreads();
        const unsigned short* wsrc = W2p + c2 * (128 * 64);
        #pragma unroll
        for (int i = 0; i < 4; ++i) {
            int id = (i << 8) + tid;      // 0..1023 16B units
            *(uint4*)(W2c + (id >> 3) * 72 + ((id & 7) << 3)) =
                *(const uint4*)(wsrc + (id << 3));
        }
        __syncthreads();
        #pragma unroll
        for (int ks = 0; ks < 2; ++ks) {
            bf16x8 a = *(const bf16x8*)(hbuf + ((wid << 4) + l16) * 264 + (c2 << 6) + (ks << 5) + (quad << 3));
            #pragma unroll
            for (int nt = 0; nt < 8; ++nt) {
                bf16x8 b = *(const bf16x8*)(W2c + ((nt << 4) + l16) * 72 + (ks << 5) + (quad << 3));
                acc2[nt] = __builtin_amdgcn_mfma_f32_16x16x32_bf16(a, b, acc2[nt], 0, 0, 0);
            }
        }
    }

    // ---------- bias + LayerNorm (in-register, 16-lane shuffle) ----------
    float b2v[8], gv[8], bev[8];
    #pragma unroll
    for (int nt = 0; nt < 8; ++nt) {
        int n = (nt << 4) + l16;
        b2v[nt] = b2[n]; gv[nt] = ln_g[n]; bev[nt] = ln_b[n];
    }
    #pragma unroll
    for (int r = 0; r < 4; ++r) {
        int e = eb + (wid << 4) + (quad << 2) + r;
        float x[8];
        float s = 0.f, s2 = 0.f;
        #pragma unroll
        for (int nt = 0; nt < 8; ++nt) {
            x[nt] = acc2[nt][r] + b2v[nt];
            s += x[nt]; s2 += x[nt] * x[nt];
        }
        #pragma unroll
        for (int m = 1; m < 16; m <<= 1) {
            s  += __shfl_xor(s, m, 64);
            s2 += __shfl_xor(s2, m, 64);
        }
        const float mu  = s * (1.f / 128.f);
        const float var = s2 * (1.f / 128.f) - mu * mu;
        const float rs  = rsqrtf(var + 1e-5f);
        if (e < E_TOT) {
            float* orow = out + (size_t)e * DOUT;
            #pragma unroll
            for (int nt = 0; nt < 8; ++nt)
                orow[(nt << 4) + l16] = (x[nt] - mu) * rs * gv[nt] + bev[nt];
        }
    }
}

extern "C" void kernel_launch(void* const* d_in, const int* in_sizes, int n_in,
                              void* d_out, int out_size, void* d_ws, size_t ws_size,
                              hipStream_t stream) {
    const float* node_attr = (const float*)d_in[0];
    const float* edge_attr = (const float*)d_in[1];
    const int*   eidx      = (const int*)d_in[2];
    const float* W1        = (const float*)d_in[3];
    const float* b1        = (const float*)d_in[4];
    const float* W2        = (const float*)d_in[5];
    const float* b2        = (const float*)d_in[6];
    const float* ln_g      = (const float*)d_in[7];
    const float* ln_b      = (const float*)d_in[8];

    unsigned short* W1p = (unsigned short*)d_ws;          // 98304 bf16
    unsigned short* W2p = W1p + 384 * 256;                // 32768 bf16

    prep_weights<<<512, 256, 0, stream>>>(W1, W2, W1p, W2p);

    const int nblocks = (E_TOT + 63) / 64;                // 4688
    edge_mlp<<<nblocks, 256, 0, stream>>>(node_attr, edge_attr, eidx,
                                          W1p, W2p, b1, b2, ln_g, ln_b,
                                          (float*)d_out);
}